// Round 7
// baseline (758.336 us; speedup 1.0000x reference)
//
#include <hip/hip_runtime.h>

// Problem constants
#define B_  8192
#define C_  64
#define K_  256
#define D_  64
#define NBT 2                  // b-tiles (256 rows) per block
#define GX  (B_ / (256 * NBT)) // 16 blocks along b
#define BC_ (B_ * C_)
#define BN_EPS 1e-5

#define WCAP_C 1024            // per-channel referee list capacity
#define DELTA  4e-3f           // top-2 gap flag band (~6 sigma of pair err)

typedef _Float16 f16x8 __attribute__((ext_vector_type(8)));
typedef __fp16   h16x2 __attribute__((ext_vector_type(2)));   // cvt_pkrtz result
typedef float    f32x4 __attribute__((ext_vector_type(4)));

// XOR swizzle for [row][128B] f16 plane: kills 32-way conflict on ds_read_b128.
__device__ __forceinline__ int swz(int row, int dbyte) {
    return (row * 128 + dbyte) ^ ((row & 7) << 4);
}

// pack 8 f32 -> f16x8 via v_cvt_pkrtz (RTZ; bias incoherent in dot-gap space)
__device__ __forceinline__ f16x8 pack8(float4 a, float4 b) {
    h16x2 p0 = __builtin_amdgcn_cvt_pkrtz(a.x, a.y);
    h16x2 p1 = __builtin_amdgcn_cvt_pkrtz(a.z, a.w);
    h16x2 p2 = __builtin_amdgcn_cvt_pkrtz(b.x, b.y);
    h16x2 p3 = __builtin_amdgcn_cvt_pkrtz(b.z, b.w);
    return (f16x8){(_Float16)p0.x, (_Float16)p0.y, (_Float16)p1.x, (_Float16)p1.y,
                   (_Float16)p2.x, (_Float16)p2.y, (_Float16)p3.x, (_Float16)p3.y};
}

// merge two packed (best, second) pairs over disjoint k-sets
#define MERGE2(B1, S1, B2, S2)                                              \
    {                                                                       \
        const float lo_ = fminf(B1, B2);                                    \
        B1 = fmaxf(B1, B2);                                                 \
        S1 = fmaxf(lo_, fmaxf(S1, S2));                                     \
    }

// ---------------------------------------------------------------------------
// Pass 1: single-pass f16 MFMA scoring (round-4 skeleton).
// Packed value|index epilogue, per-j-slot chains. 512 thr, 32 KiB LDS.
// Near-ties (gap < DELTA) -> per-channel worklist -> fp64 referee.
// ---------------------------------------------------------------------------
__global__ __launch_bounds__(512, 6) void dpq_mfma(
    const float* __restrict__ x,        // (B, C, D)
    const float* __restrict__ cent,     // (C, K, D)
    const float* __restrict__ gamma,    // (C)
    float* __restrict__ out,            // [codes BC][raw mse BC][centroids]
    float* __restrict__ part_sum,       // (C, GX)
    float* __restrict__ part_sq,        // (C, GX)
    int* __restrict__ wcount,           // (C)
    int* __restrict__ worklist)         // (C, WCAP_C) stores b
{
    __shared__ char lds[32768];
    const int c   = blockIdx.y;
    const int tid = threadIdx.x;
    const float sgn = (gamma[c] < 0.0f) ? -1.0f : 1.0f;   // fold BN sign

    // ---- stage centroids: 512 threads, each converts half a k-row ----
    {
        const int row = tid >> 1, half = tid & 1;
        const float* g = cent + ((size_t)c * K_ + row) * D_ + half * 32;
#pragma unroll
        for (int q = 0; q < 4; ++q) {
            float4 u0 = *(const float4*)(g + q * 8);
            float4 u1 = *(const float4*)(g + q * 8 + 4);
            u0.x *= sgn; u0.y *= sgn; u0.z *= sgn; u0.w *= sgn;
            u1.x *= sgn; u1.y *= sgn; u1.z *= sgn; u1.w *= sgn;
            *(f16x8*)(lds + swz(row, half * 64 + q * 16)) = pack8(u0, u1);
        }
    }
    __syncthreads();

    const int wid = tid >> 6, lane = tid & 63;
    const int col = lane & 15, grp = lane >> 4;

    // channel-sum state: per-j-slot, per-T (8 independent chains each)
    float accsA[4] = {0, 0, 0, 0}, accsB[4] = {0, 0, 0, 0};
    float accqA[4] = {0, 0, 0, 0}, accqB[4] = {0, 0, 0, 0};

    for (int bt = 0; bt < NBT; ++bt) {
        const int b0 = (blockIdx.x * NBT + bt) * 256 + wid * 32;

        // x fragments: 2 b-subtiles x 2 d-halves
        f16x8 xf00, xf01, xf10, xf11;
        {
            const float* xr0 = x + ((size_t)(b0 + col) * C_ + c) * D_ + grp * 8;
            const float* xr1 = xr0 + 16 * (size_t)C_ * D_;
            xf00 = pack8(*(const float4*)xr0, *(const float4*)(xr0 + 4));
            xf01 = pack8(*(const float4*)(xr0 + 32), *(const float4*)(xr0 + 36));
            xf10 = pack8(*(const float4*)xr1, *(const float4*)(xr1 + 4));
            xf11 = pack8(*(const float4*)(xr1 + 32), *(const float4*)(xr1 + 36));
        }

        // per-j-slot packed top-2 state (8 independent chains per array)
        float bestA[4], secA[4], bestB[4], secB[4];
#pragma unroll
        for (int j = 0; j < 4; ++j) {
            bestA[j] = -3.4e38f; secA[j] = -3.4e38f;
            bestB[j] = -3.4e38f; secB[j] = -3.4e38f;
        }
        int org[4];                     // running k index per slot
#pragma unroll
        for (int j = 0; j < 4; ++j) org[j] = grp * 4 + j;

#pragma unroll
        for (int t = 0; t < 16; ++t) {
            const f16x8 a0 = *(const f16x8*)(lds + swz(t * 16 + col,      grp * 16));
            const f16x8 a1 = *(const f16x8*)(lds + swz(t * 16 + col, 64 + grp * 16));

            f32x4 pA = {0.f, 0.f, 0.f, 0.f};
            pA = __builtin_amdgcn_mfma_f32_16x16x32_f16(a0, xf00, pA, 0, 0, 0);
            pA = __builtin_amdgcn_mfma_f32_16x16x32_f16(a1, xf01, pA, 0, 0, 0);
            f32x4 pB = {0.f, 0.f, 0.f, 0.f};
            pB = __builtin_amdgcn_mfma_f32_16x16x32_f16(a0, xf10, pB, 0, 0, 0);
            pB = __builtin_amdgcn_mfma_f32_16x16x32_f16(a1, xf11, pB, 0, 0, 0);

#pragma unroll
            for (int j = 0; j < 4; ++j) {
                const float r0 = pA[j], r1 = pB[j];
                accsA[j] += r0;
                accqA[j] = fmaf(r0, r0, accqA[j]);
                accsB[j] += r1;
                accqB[j] = fmaf(r1, r1, accqB[j]);
                // pack value|k: one v_and_or_b32 each
                const float pk0 = __uint_as_float(
                    (__float_as_uint(r0) & 0xFFFFFF00u) | (unsigned)org[j]);
                const float pk1 = __uint_as_float(
                    (__float_as_uint(r1) & 0xFFFFFF00u) | (unsigned)org[j]);
                secA[j]  = __builtin_amdgcn_fmed3f(pk0, bestA[j], secA[j]);
                bestA[j] = fmaxf(bestA[j], pk0);
                secB[j]  = __builtin_amdgcn_fmed3f(pk1, bestB[j], secB[j]);
                bestB[j] = fmaxf(bestB[j], pk1);
            }
#pragma unroll
            for (int j = 0; j < 4; ++j) org[j] += 16;
        }

        // ---- reduce 4 j-slots, then cross-lane (bits 4,5), per T ----
#pragma unroll
        for (int T = 0; T < 2; ++T) {
            float b0v = T ? bestB[0] : bestA[0], s0v = T ? secB[0] : secA[0];
            float b1v = T ? bestB[1] : bestA[1], s1v = T ? secB[1] : secA[1];
            float b2v = T ? bestB[2] : bestA[2], s2v = T ? secB[2] : secA[2];
            float b3v = T ? bestB[3] : bestA[3], s3v = T ? secB[3] : secA[3];
            MERGE2(b0v, s0v, b1v, s1v);
            MERGE2(b2v, s2v, b3v, s3v);
            MERGE2(b0v, s0v, b2v, s2v);
#pragma unroll
            for (int m = 16; m <= 32; m <<= 1) {
                const float ob = __shfl_xor(b0v, m);
                const float os = __shfl_xor(s0v, m);
                MERGE2(b0v, s0v, ob, os);
            }
            if (grp == 0) {
                const int b = b0 + T * 16 + col;
                const size_t idx = (size_t)b * C_ + c;
                const unsigned bits = __float_as_uint(b0v);
                out[idx] = (float)(bits & 255u);                    // code
                out[(size_t)BC_ + idx] = __uint_as_float(bits & 0xFFFFFF00u);
                if (b0v - s0v < DELTA && worklist) {
                    const int slot = atomicAdd(&wcount[c], 1);
                    if (slot < WCAP_C) worklist[c * WCAP_C + slot] = b;
                }
            }
        }
    }

    // ---- channel sum / sumsq block reduction ----
    float accs = ((accsA[0] + accsA[1]) + (accsA[2] + accsA[3]))
               + ((accsB[0] + accsB[1]) + (accsB[2] + accsB[3]));
    float accq = ((accqA[0] + accqA[1]) + (accqA[2] + accqA[3]))
               + ((accqB[0] + accqB[1]) + (accqB[2] + accqB[3]));
#pragma unroll
    for (int m = 1; m <= 32; m <<= 1) {
        accs += __shfl_xor(accs, m);
        accq += __shfl_xor(accq, m);
    }
    __syncthreads();                    // plane dead; reuse LDS
    float* red = (float*)lds;
    if (lane == 0) { red[wid] = accs; red[8 + wid] = accq; }
    __syncthreads();
    if (tid == 0) {
        float s = 0.f, q = 0.f;
#pragma unroll
        for (int w = 0; w < 8; ++w) { s += red[w]; q += red[8 + w]; }
        part_sum[c * GX + blockIdx.x] = s;
        part_sq [c * GX + blockIdx.x] = q;
    }
}

// ---------------------------------------------------------------------------
// Referee: exact fp64 re-score of flagged pairs, channel-bucketed.
// grid (64, 8): block (c, s) stages channel c's centroids (f32, bank-swizzled)
// in 64 KiB LDS once; each WAVE takes one entry (lane = 4 k's), fp64 dot.
// ---------------------------------------------------------------------------
__global__ __launch_bounds__(256) void dpq_referee(
    const float* __restrict__ x,
    const float* __restrict__ cent,
    const float* __restrict__ gamma,
    const int* __restrict__ wcount,
    const int* __restrict__ worklist,
    float* __restrict__ out)
{
    __shared__ float cl[K_ * D_];       // 64 KiB exact centroids
    const int c = blockIdx.x;
    int n = wcount[c];
    if (n > WCAP_C) n = WCAP_C;
    if (n == 0) return;
    const int t = threadIdx.x;          // 0..255 = k row to stage
    const float sgnf = (gamma[c] < 0.0f) ? -1.0f : 1.0f;

    // stage row t with d-swizzle (d ^ (k&31)) -> conflict-free lane reads
    {
        const float* g = cent + ((size_t)c * K_ + t) * D_;
#pragma unroll 8
        for (int d = 0; d < D_; ++d)
            cl[t * D_ + (d ^ (t & 31))] = g[d];
    }
    __syncthreads();

    const int wid = t >> 6, lane = t & 63;
    for (int i = blockIdx.y * 4 + wid; i < n; i += gridDim.y * 4) {
        const int b = worklist[c * WCAP_C + i];
        const float* xr = x + ((size_t)b * C_ + c) * D_;
        double bv = -1.0e300;
        int bk = 0;
#pragma unroll
        for (int q = 0; q < 4; ++q) {
            const int k = q * 64 + lane;            // ascending per lane
            const int sw = k & 31;
            double s = 0.0;
#pragma unroll 8
            for (int d = 0; d < D_; ++d)
                s += (double)xr[d] * (double)cl[k * D_ + (d ^ sw)];
            s *= (double)sgnf;
            if (s > bv) { bv = s; bk = k; }
        }
#pragma unroll
        for (int m = 1; m <= 32; m <<= 1) {
            const double ov = __shfl_xor(bv, m);
            const int   ok = __shfl_xor(bk, m);
            if (ov > bv || (ov == bv && ok < bk)) { bv = ov; bk = ok; }
        }
        if (lane == 0) {
            const size_t idx = (size_t)b * C_ + c;
            out[idx] = (float)bk;
            out[(size_t)BC_ + idx] = (float)bv;
        }
    }
}

// ---------------------------------------------------------------------------
// Per-channel BN stats on sign-folded scores.
// ---------------------------------------------------------------------------
__global__ void dpq_stats(
    const float* __restrict__ part_sum,
    const float* __restrict__ part_sq,
    const float* __restrict__ gamma,
    const float* __restrict__ beta,
    float* __restrict__ scale_out,
    float* __restrict__ shift_out)
{
    const int c = threadIdx.x;
    if (c >= C_) return;
    double s = 0.0, q = 0.0;
    for (int i = 0; i < GX; ++i) {
        s += (double)part_sum[c * GX + i];
        q += (double)part_sq [c * GX + i];
    }
    const double n    = (double)B_ * (double)K_;
    const double mean = s / n;
    const double var  = q / n - mean * mean;      // biased, matches reference
    const double sc   = fabs((double)gamma[c]) / sqrt(var + BN_EPS);
    scale_out[c] = (float)sc;
    shift_out[c] = (float)((double)beta[c] - mean * sc);
}

// ---------------------------------------------------------------------------
// Apply per-channel affine to stored raw max. gamma==0 -> constant channel.
// ---------------------------------------------------------------------------
__global__ __launch_bounds__(256) void dpq_apply(
    float* __restrict__ out,
    const float* __restrict__ scale,
    const float* __restrict__ shift)
{
    const int idx = blockIdx.x * 256 + threadIdx.x;   // over B*C, c fastest
    const int c = idx & (C_ - 1);
    const float sc = scale[c];
    const float sh = shift[c];
    if (sc == 0.0f) {
        out[idx] = 0.0f;
        out[(size_t)BC_ + idx] = sh;
    } else {
        out[(size_t)BC_ + idx] = fmaf(out[(size_t)BC_ + idx], sc, sh);
    }
}

// ---------------------------------------------------------------------------
extern "C" void kernel_launch(void* const* d_in, const int* in_sizes, int n_in,
                              void* d_out, int out_size, void* d_ws, size_t ws_size,
                              hipStream_t stream)
{
    const float* x     = (const float*)d_in[0];
    const float* cent  = (const float*)d_in[1];
    const float* gamma = (const float*)d_in[2];
    const float* beta  = (const float*)d_in[3];
    float* out = (float*)d_out;
    float* ws  = (float*)d_ws;

    // ws layout (4B units): [0,1024) part_sum | [1024,2048) part_sq
    // [2048,2112) scale | [2112,2176) shift | [2176,2240) wcount[64]
    // [2240, 2240+64*WCAP_C) worklist
    float* part_sum = ws;
    float* part_sq  = ws + 1024;
    float* scale    = ws + 2048;
    float* shift    = ws + 2112;
    int*   wcount   = (int*)(ws + 2176);
    int*   worklist = (int*)(ws + 2240);
    const size_t need = (size_t)(2240 + C_ * WCAP_C) * 4;
    if (ws_size < need) { wcount = nullptr; worklist = nullptr; }

    if (wcount)
        (void)hipMemsetAsync(wcount, 0, C_ * sizeof(int), stream);

    dim3 g1(GX, C_);   // (16, 64)
    hipLaunchKernelGGL(dpq_mfma, g1, dim3(512), 0, stream,
                       x, cent, gamma, out, part_sum, part_sq, wcount, worklist);
    if (wcount)
        hipLaunchKernelGGL(dpq_referee, dim3(C_, 8), dim3(256), 0, stream,
                           x, cent, gamma, wcount, worklist, out);
    hipLaunchKernelGGL(dpq_stats, dim3(1), dim3(64), 0, stream,
                       part_sum, part_sq, gamma, beta, scale, shift);
    hipLaunchKernelGGL(dpq_apply, dim3(BC_ / 256), dim3(256), 0, stream,
                       out, scale, shift);
    (void)hipMemcpyAsync(out + 2 * (size_t)BC_, cent,
                         (size_t)C_ * K_ * D_ * sizeof(float),
                         hipMemcpyDeviceToDevice, stream);
}

// Round 8
// 111.898 us; speedup vs baseline: 6.7771x; 6.7771x over previous
//
#include <hip/hip_runtime.h>

// Problem constants
#define B_  8192
#define C_  64
#define K_  256
#define D_  64
#define NBT     2              // b-tiles per block
#define ROWS_BT 512            // rows per b-tile (8 waves x 64 rows)
#define GX  (B_ / (ROWS_BT * NBT))   // 8 blocks along b
#define BC_ (B_ * C_)
#define BN_EPS 1e-5

#define WCAP_C 1024            // per-channel referee list capacity
#define DELTA  4e-3f           // top-2 gap flag band (~6 sigma of f16 pair err)

typedef _Float16 f16x8 __attribute__((ext_vector_type(8)));
typedef float    f32x4 __attribute__((ext_vector_type(4)));

// XOR swizzle for [row][128B] f16 plane: kills 32-way bank conflict on b128.
__device__ __forceinline__ int swz(int row, int dbyte) {
    return (row * 128 + dbyte) ^ ((row & 7) << 4);
}

// plain-cast f32x8 -> f16x8 (round-4 known-good conversion)
__device__ __forceinline__ f16x8 cvt8(const float* p) {
    float4 u0 = *(const float4*)p;
    float4 u1 = *(const float4*)(p + 4);
    return (f16x8){(_Float16)u0.x, (_Float16)u0.y, (_Float16)u0.z, (_Float16)u0.w,
                   (_Float16)u1.x, (_Float16)u1.y, (_Float16)u1.z, (_Float16)u1.w};
}

// merge two packed (best, second) pairs over disjoint k-sets
#define MERGE2(B1, S1, B2, S2)                                              \
    {                                                                       \
        const float lo_ = fminf(B1, B2);                                    \
        B1 = fmaxf(B1, B2);                                                 \
        S1 = fmaxf(lo_, fmaxf(S1, S2));                                     \
    }

// ---------------------------------------------------------------------------
// Pass 1: single-pass f16 MFMA scoring. 512 thr, 32 KiB LDS plane.
// Each wave owns 64 b-rows (4 MFMA sub-tiles) -> 2 ds_reads feed 16 scores.
// Packed value|index top-2 epilogue; near-ties -> worklist -> fp64 referee.
// ---------------------------------------------------------------------------
__global__ __launch_bounds__(512, 4) void dpq_mfma(
    const float* __restrict__ x,        // (B, C, D)
    const float* __restrict__ cent,     // (C, K, D)
    const float* __restrict__ gamma,    // (C)
    float* __restrict__ out,            // [codes BC][raw mse BC][centroids]
    float* __restrict__ part_sum,       // (C, GX)
    float* __restrict__ part_sq,        // (C, GX)
    int* __restrict__ wcount,           // (C)
    int* __restrict__ worklist)         // (C, WCAP_C) stores b
{
    __shared__ char lds[32768];
    const int c   = blockIdx.y;
    const int tid = threadIdx.x;
    const float sgn = (gamma[c] < 0.0f) ? -1.0f : 1.0f;   // fold BN sign

    // ---- stage centroids: 512 threads, each converts half a k-row ----
    {
        const int row = tid >> 1, half = tid & 1;
        const float* g = cent + ((size_t)c * K_ + row) * D_ + half * 32;
#pragma unroll
        for (int q = 0; q < 4; ++q) {
            float v[8];
#pragma unroll
            for (int j = 0; j < 8; ++j) v[j] = g[q * 8 + j] * sgn;
            f16x8 h = {(_Float16)v[0], (_Float16)v[1], (_Float16)v[2], (_Float16)v[3],
                       (_Float16)v[4], (_Float16)v[5], (_Float16)v[6], (_Float16)v[7]};
            *(f16x8*)(lds + swz(row, half * 64 + q * 16)) = h;
        }
    }
    __syncthreads();

    const int wid = tid >> 6, lane = tid & 63;
    const int col = lane & 15, grp = lane >> 4;
    const unsigned g4 = (unsigned)(grp * 4);

    // per-T channel-sum chains (static-indexed, fully unrolled use only)
    float taccs[4] = {0.f, 0.f, 0.f, 0.f};
    float taccq[4] = {0.f, 0.f, 0.f, 0.f};

    for (int bt = 0; bt < NBT; ++bt) {
        const int b0 = blockIdx.x * (ROWS_BT * NBT) + bt * ROWS_BT + wid * 64;

        // x fragments: 4 b-subtiles (T) x 2 d-halves
        f16x8 xfa[4], xfb[4];
        {
            const float* xb = x + ((size_t)(b0 + col) * C_ + c) * D_ + grp * 8;
            const size_t st16 = (size_t)16 * C_ * D_;
#pragma unroll
            for (int T = 0; T < 4; ++T) {
                xfa[T] = cvt8(xb + T * st16);
                xfb[T] = cvt8(xb + T * st16 + 32);
            }
        }

        float bestv[4], secv[4];
#pragma unroll
        for (int T = 0; T < 4; ++T) { bestv[T] = -3.4e38f; secv[T] = -3.4e38f; }

#pragma unroll 4
        for (int t = 0; t < 16; ++t) {
            const f16x8 a0 = *(const f16x8*)(lds + swz(t * 16 + col,      grp * 16));
            const f16x8 a1 = *(const f16x8*)(lds + swz(t * 16 + col, 64 + grp * 16));

            f32x4 p[4];
#pragma unroll
            for (int T = 0; T < 4; ++T) {
                f32x4 acc = {0.f, 0.f, 0.f, 0.f};
                acc = __builtin_amdgcn_mfma_f32_16x16x32_f16(a0, xfa[T], acc, 0, 0, 0);
                acc = __builtin_amdgcn_mfma_f32_16x16x32_f16(a1, xfb[T], acc, 0, 0, 0);
                p[T] = acc;
            }

            const unsigned kt = ((unsigned)t << 4) | g4;   // t*16 + grp*4
#pragma unroll
            for (int j = 0; j < 4; ++j) {
                const unsigned kj = kt + j;
#pragma unroll
                for (int T = 0; T < 4; ++T) {
                    const float r = p[T][j];
                    taccs[T] += r;
                    taccq[T] = fmaf(r, r, taccq[T]);
                    const float pk = __uint_as_float(
                        (__float_as_uint(r) & 0xFFFFFF00u) | kj);
                    secv[T]  = __builtin_amdgcn_fmed3f(pk, bestv[T], secv[T]);
                    bestv[T] = fmaxf(bestv[T], pk);
                }
            }
        }

        // ---- cross-lane top-2 merge (same-col lanes differ in bits 4,5) ----
#pragma unroll
        for (int T = 0; T < 4; ++T) {
            float bv = bestv[T], sv = secv[T];
#pragma unroll
            for (int m = 16; m <= 32; m <<= 1) {
                const float ob = __shfl_xor(bv, m);
                const float os = __shfl_xor(sv, m);
                MERGE2(bv, sv, ob, os);
            }
            if (grp == 0) {
                const int b = b0 + T * 16 + col;
                const size_t idx = (size_t)b * C_ + c;
                const unsigned bits = __float_as_uint(bv);
                out[idx] = (float)(bits & 255u);                       // code
                out[(size_t)BC_ + idx] = __uint_as_float(bits & 0xFFFFFF00u);
                if (bv - sv < DELTA && worklist) {
                    const int slot = atomicAdd(&wcount[c], 1);
                    if (slot < WCAP_C) worklist[c * WCAP_C + slot] = b;
                }
            }
        }
    }

    // ---- channel sum / sumsq block reduction ----
    float accs = (taccs[0] + taccs[1]) + (taccs[2] + taccs[3]);
    float accq = (taccq[0] + taccq[1]) + (taccq[2] + taccq[3]);
#pragma unroll
    for (int m = 1; m <= 32; m <<= 1) {
        accs += __shfl_xor(accs, m);
        accq += __shfl_xor(accq, m);
    }
    __syncthreads();                    // plane dead; reuse LDS
    float* red = (float*)lds;
    if (lane == 0) { red[wid] = accs; red[8 + wid] = accq; }
    __syncthreads();
    if (tid == 0) {
        float s = 0.f, q = 0.f;
#pragma unroll
        for (int w = 0; w < 8; ++w) { s += red[w]; q += red[8 + w]; }
        part_sum[c * GX + blockIdx.x] = s;
        part_sq [c * GX + blockIdx.x] = q;
    }
}

// ---------------------------------------------------------------------------
// Referee: exact fp64 re-score of flagged pairs, channel-bucketed.
// grid (64, 8): block (c, s) stages channel c's centroids (f32, bank-swizzled)
// in 64 KiB LDS once; each WAVE takes one entry (lane = 4 k's), fp64 dot.
// ---------------------------------------------------------------------------
__global__ __launch_bounds__(256) void dpq_referee(
    const float* __restrict__ x,
    const float* __restrict__ cent,
    const float* __restrict__ gamma,
    const int* __restrict__ wcount,
    const int* __restrict__ worklist,
    float* __restrict__ out)
{
    __shared__ float cl[K_ * D_];       // 64 KiB exact centroids
    const int c = blockIdx.x;
    int n = wcount[c];
    if (n > WCAP_C) n = WCAP_C;
    if (n == 0) return;
    const int t = threadIdx.x;          // 0..255 = k row to stage
    const float sgnf = (gamma[c] < 0.0f) ? -1.0f : 1.0f;

    // stage row t with d-swizzle (d ^ (k&31)) -> conflict-free lane reads
    {
        const float* g = cent + ((size_t)c * K_ + t) * D_;
#pragma unroll 8
        for (int d = 0; d < D_; ++d)
            cl[t * D_ + (d ^ (t & 31))] = g[d];
    }
    __syncthreads();

    const int wid = t >> 6, lane = t & 63;
    for (int i = blockIdx.y * 4 + wid; i < n; i += gridDim.y * 4) {
        const int b = worklist[c * WCAP_C + i];
        const float* xr = x + ((size_t)b * C_ + c) * D_;
        double bv = -1.0e300;
        int bk = 0;
#pragma unroll
        for (int q = 0; q < 4; ++q) {
            const int k = q * 64 + lane;            // ascending per lane
            const int sw = k & 31;
            double s = 0.0;
#pragma unroll 8
            for (int d = 0; d < D_; ++d)
                s += (double)xr[d] * (double)cl[k * D_ + (d ^ sw)];
            s *= (double)sgnf;
            if (s > bv) { bv = s; bk = k; }
        }
#pragma unroll
        for (int m = 1; m <= 32; m <<= 1) {
            const double ov = __shfl_xor(bv, m);
            const int   ok = __shfl_xor(bk, m);
            if (ov > bv || (ov == bv && ok < bk)) { bv = ov; bk = ok; }
        }
        if (lane == 0) {
            const size_t idx = (size_t)b * C_ + c;
            out[idx] = (float)bk;
            out[(size_t)BC_ + idx] = (float)bv;
        }
    }
}

// ---------------------------------------------------------------------------
// Per-channel BN stats on sign-folded scores.
// ---------------------------------------------------------------------------
__global__ void dpq_stats(
    const float* __restrict__ part_sum,
    const float* __restrict__ part_sq,
    const float* __restrict__ gamma,
    const float* __restrict__ beta,
    float* __restrict__ scale_out,
    float* __restrict__ shift_out)
{
    const int c = threadIdx.x;
    if (c >= C_) return;
    double s = 0.0, q = 0.0;
    for (int i = 0; i < GX; ++i) {
        s += (double)part_sum[c * GX + i];
        q += (double)part_sq [c * GX + i];
    }
    const double n    = (double)B_ * (double)K_;
    const double mean = s / n;
    const double var  = q / n - mean * mean;      // biased, matches reference
    const double sc   = fabs((double)gamma[c]) / sqrt(var + BN_EPS);
    scale_out[c] = (float)sc;
    shift_out[c] = (float)((double)beta[c] - mean * sc);
}

// ---------------------------------------------------------------------------
// Apply per-channel affine to stored raw max. gamma==0 -> constant channel.
// ---------------------------------------------------------------------------
__global__ __launch_bounds__(256) void dpq_apply(
    float* __restrict__ out,
    const float* __restrict__ scale,
    const float* __restrict__ shift)
{
    const int idx = blockIdx.x * 256 + threadIdx.x;   // over B*C, c fastest
    const int c = idx & (C_ - 1);
    const float sc = scale[c];
    const float sh = shift[c];
    if (sc == 0.0f) {
        out[idx] = 0.0f;
        out[(size_t)BC_ + idx] = sh;
    } else {
        out[(size_t)BC_ + idx] = fmaf(out[(size_t)BC_ + idx], sc, sh);
    }
}

// ---------------------------------------------------------------------------
extern "C" void kernel_launch(void* const* d_in, const int* in_sizes, int n_in,
                              void* d_out, int out_size, void* d_ws, size_t ws_size,
                              hipStream_t stream)
{
    const float* x     = (const float*)d_in[0];
    const float* cent  = (const float*)d_in[1];
    const float* gamma = (const float*)d_in[2];
    const float* beta  = (const float*)d_in[3];
    float* out = (float*)d_out;
    float* ws  = (float*)d_ws;

    // ws layout (4B units): [0,512) part_sum | [512,1024) part_sq
    // [1024,1088) scale | [1088,1152) shift | [1152,1216) wcount[64]
    // [1216, 1216+64*WCAP_C) worklist
    float* part_sum = ws;
    float* part_sq  = ws + 512;
    float* scale    = ws + 1024;
    float* shift    = ws + 1088;
    int*   wcount   = (int*)(ws + 1152);
    int*   worklist = (int*)(ws + 1216);
    const size_t need = (size_t)(1216 + C_ * WCAP_C) * 4;
    if (ws_size < need) { wcount = nullptr; worklist = nullptr; }

    if (wcount)
        (void)hipMemsetAsync(wcount, 0, C_ * sizeof(int), stream);

    dim3 g1(GX, C_);   // (8, 64)
    hipLaunchKernelGGL(dpq_mfma, g1, dim3(512), 0, stream,
                       x, cent, gamma, out, part_sum, part_sq, wcount, worklist);
    if (wcount)
        hipLaunchKernelGGL(dpq_referee, dim3(C_, 8), dim3(256), 0, stream,
                           x, cent, gamma, wcount, worklist, out);
    hipLaunchKernelGGL(dpq_stats, dim3(1), dim3(64), 0, stream,
                       part_sum, part_sq, gamma, beta, scale, shift);
    hipLaunchKernelGGL(dpq_apply, dim3(BC_ / 256), dim3(256), 0, stream,
                       out, scale, shift);
    (void)hipMemcpyAsync(out + 2 * (size_t)BC_, cent,
                         (size_t)C_ * K_ * D_ * sizeof(float),
                         hipMemcpyDeviceToDevice, stream);
}

// Round 9
// 100.646 us; speedup vs baseline: 7.5347x; 1.1118x over previous
//
#include <hip/hip_runtime.h>

// Problem constants
#define B_  8192
#define C_  64
#define K_  256
#define D_  64
#define NBT     2              // b-tiles per block
#define ROWS_BT 512            // rows per b-tile (8 waves x 64 rows)
#define GX  (B_ / (ROWS_BT * NBT))   // 8 blocks along b
#define BC_ (B_ * C_)
#define BN_EPS 1e-5

#define WCAP_C 1024            // per-channel referee list capacity
#define DELTA  2.5e-3f         // top-2 gap flag band (r4-validated for RTNE f16)

typedef _Float16 f16x8 __attribute__((ext_vector_type(8)));
typedef float    f32x4 __attribute__((ext_vector_type(4)));

// XOR swizzle for [row][128B] f16 plane: kills 32-way bank conflict on b128.
__device__ __forceinline__ int swz(int row, int dbyte) {
    return (row * 128 + dbyte) ^ ((row & 7) << 4);
}

// plain-cast f32x8 -> f16x8 (known-good RTNE conversion)
__device__ __forceinline__ f16x8 cvt8(const float* p) {
    float4 u0 = *(const float4*)p;
    float4 u1 = *(const float4*)(p + 4);
    return (f16x8){(_Float16)u0.x, (_Float16)u0.y, (_Float16)u0.z, (_Float16)u0.w,
                   (_Float16)u1.x, (_Float16)u1.y, (_Float16)u1.z, (_Float16)u1.w};
}

// merge two packed (best, second) pairs over disjoint k-sets
#define MERGE2(B1, S1, B2, S2)                                              \
    {                                                                       \
        const float lo_ = fminf(B1, B2);                                    \
        B1 = fmaxf(B1, B2);                                                 \
        S1 = fmaxf(lo_, fmaxf(S1, S2));                                     \
    }

// ---------------------------------------------------------------------------
// Prep: per-channel centroid column-sums (for the virtual sum-row) + zero the
// referee counters. Replaces the old hipMemsetAsync node.
// ---------------------------------------------------------------------------
__global__ __launch_bounds__(64) void dpq_prep(
    const float* __restrict__ cent, float* __restrict__ csum,
    int* __restrict__ wcount)
{
    const int c = blockIdx.x, d = threadIdx.x;
    const float* g = cent + (size_t)c * K_ * D_ + d;
    float s = 0.f;
#pragma unroll 8
    for (int k = 0; k < K_; ++k) s += g[(size_t)k * D_];
    csum[c * D_ + d] = s;
    if (d == 0) wcount[c] = 0;
}

// ---------------------------------------------------------------------------
// Pass 1: single-pass f16 MFMA scoring. 512 thr, 32 KiB plane + 2 KiB cs-tile.
// Each wave owns 64 b-rows (4 sub-tiles); 16 k-steps + 1 virtual sum-step.
// Packed value|index top-2 epilogue; near-ties -> worklist -> fp64 referee.
// ---------------------------------------------------------------------------
__global__ __launch_bounds__(512, 4) void dpq_mfma(
    const float* __restrict__ x,        // (B, C, D)
    const float* __restrict__ cent,     // (C, K, D)
    const float* __restrict__ gamma,    // (C)
    const float* __restrict__ csum,     // (C, D) centroid column sums
    float* __restrict__ out,            // [codes BC][raw mse BC][centroids]
    float* __restrict__ part_sum,       // (C, GX)
    float* __restrict__ part_sq,        // (C, GX)
    int* __restrict__ wcount,           // (C)
    int* __restrict__ worklist)         // (C, WCAP_C) stores b
{
    __shared__ char lds[34816];         // [0,32K) k-plane | [32K,34K) cs-tile
    const int c   = blockIdx.y;
    const int tid = threadIdx.x;
    const float sgn = (gamma[c] < 0.0f) ? -1.0f : 1.0f;   // fold BN sign

    // ---- stage centroids: 512 threads, each converts half a k-row ----
    {
        const int row = tid >> 1, half = tid & 1;
        const float* g = cent + ((size_t)c * K_ + row) * D_ + half * 32;
#pragma unroll
        for (int q = 0; q < 4; ++q) {
            float v[8];
#pragma unroll
            for (int j = 0; j < 8; ++j) v[j] = g[q * 8 + j] * sgn;
            f16x8 h = {(_Float16)v[0], (_Float16)v[1], (_Float16)v[2], (_Float16)v[3],
                       (_Float16)v[4], (_Float16)v[5], (_Float16)v[6], (_Float16)v[7]};
            *(f16x8*)(lds + swz(row, half * 64 + q * 16)) = h;
        }
    }
    // ---- stage cs-tile: row 0 = sign-folded centroid sum, rows 1-15 = 0 ----
    if (tid < 128) {
        const int row = tid >> 3, q = tid & 7;
        f16x8 h = {0, 0, 0, 0, 0, 0, 0, 0};
        if (row == 0) {
            const float* cs = csum + c * D_ + q * 8;
#pragma unroll
            for (int j = 0; j < 8; ++j) h[j] = (_Float16)(cs[j] * sgn);
        }
        *(f16x8*)(lds + 32768 + swz(row, q * 16)) = h;
    }
    __syncthreads();

    const int wid = tid >> 6, lane = tid & 63;
    const int col = lane & 15, grp = lane >> 4;
    const unsigned g4 = (unsigned)(grp * 4);

    float taccs[4] = {0.f, 0.f, 0.f, 0.f};   // fed by virtual sum-step only
    float taccq[4] = {0.f, 0.f, 0.f, 0.f};

    for (int bt = 0; bt < NBT; ++bt) {
        const int b0 = blockIdx.x * (ROWS_BT * NBT) + bt * ROWS_BT + wid * 64;

        // x fragments: 4 b-subtiles (T) x 2 d-halves
        f16x8 xfa[4], xfb[4];
        {
            const float* xb = x + ((size_t)(b0 + col) * C_ + c) * D_ + grp * 8;
            const size_t st16 = (size_t)16 * C_ * D_;
#pragma unroll
            for (int T = 0; T < 4; ++T) {
                xfa[T] = cvt8(xb + T * st16);
                xfb[T] = cvt8(xb + T * st16 + 32);
            }
        }

        float bestv[4], secv[4];
#pragma unroll
        for (int T = 0; T < 4; ++T) { bestv[T] = -3.4e38f; secv[T] = -3.4e38f; }

#pragma unroll 4
        for (int t = 0; t < 16; ++t) {
            const f16x8 a0 = *(const f16x8*)(lds + swz(t * 16 + col,      grp * 16));
            const f16x8 a1 = *(const f16x8*)(lds + swz(t * 16 + col, 64 + grp * 16));

            f32x4 p[4];
#pragma unroll
            for (int T = 0; T < 4; ++T) {
                f32x4 acc = {0.f, 0.f, 0.f, 0.f};
                acc = __builtin_amdgcn_mfma_f32_16x16x32_f16(a0, xfa[T], acc, 0, 0, 0);
                acc = __builtin_amdgcn_mfma_f32_16x16x32_f16(a1, xfb[T], acc, 0, 0, 0);
                p[T] = acc;
            }

            const unsigned kt = ((unsigned)t << 4) | g4;   // t*16 + grp*4
#pragma unroll
            for (int j = 0; j < 4; ++j) {
                const unsigned kj = kt + j;
#pragma unroll
                for (int T = 0; T < 4; ++T) {
                    const float r = p[T][j];
                    taccq[T] = fmaf(r, r, taccq[T]);
                    const float pk = __uint_as_float(
                        (__float_as_uint(r) & 0xFFFFFF00u) | kj);
                    secv[T]  = __builtin_amdgcn_fmed3f(pk, bestv[T], secv[T]);
                    bestv[T] = fmaxf(bestv[T], pk);
                }
            }
        }

        // ---- virtual sum-step: row 0 of cs-tile = sum over all k ----
        {
            const f16x8 a0v = *(const f16x8*)(lds + 32768 + swz(col,      grp * 16));
            const f16x8 a1v = *(const f16x8*)(lds + 32768 + swz(col, 64 + grp * 16));
#pragma unroll
            for (int T = 0; T < 4; ++T) {
                f32x4 pv = {0.f, 0.f, 0.f, 0.f};
                pv = __builtin_amdgcn_mfma_f32_16x16x32_f16(a0v, xfa[T], pv, 0, 0, 0);
                pv = __builtin_amdgcn_mfma_f32_16x16x32_f16(a1v, xfb[T], pv, 0, 0, 0);
                taccs[T] += pv[0];   // nonzero only where k-row==0 (grp0,j0 lanes)
            }
        }

        // ---- cross-lane top-2 merge (same-col lanes differ in bits 4,5) ----
#pragma unroll
        for (int T = 0; T < 4; ++T) {
            float bv = bestv[T], sv = secv[T];
#pragma unroll
            for (int m = 16; m <= 32; m <<= 1) {
                const float ob = __shfl_xor(bv, m);
                const float os = __shfl_xor(sv, m);
                MERGE2(bv, sv, ob, os);
            }
            if (grp == 0) {
                const int b = b0 + T * 16 + col;
                const size_t idx = (size_t)b * C_ + c;
                const unsigned bits = __float_as_uint(bv);
                out[idx] = (float)(bits & 255u);                       // code
                out[(size_t)BC_ + idx] = __uint_as_float(bits & 0xFFFFFF00u);
                if (bv - sv < DELTA && worklist) {
                    const int slot = atomicAdd(&wcount[c], 1);
                    if (slot < WCAP_C) worklist[c * WCAP_C + slot] = b;
                }
            }
        }
    }

    // ---- channel sum / sumsq block reduction ----
    float accs = (taccs[0] + taccs[1]) + (taccs[2] + taccs[3]);
    float accq = (taccq[0] + taccq[1]) + (taccq[2] + taccq[3]);
#pragma unroll
    for (int m = 1; m <= 32; m <<= 1) {
        accs += __shfl_xor(accs, m);
        accq += __shfl_xor(accq, m);
    }
    __syncthreads();                    // plane dead; reuse LDS
    float* red = (float*)lds;
    if (lane == 0) { red[wid] = accs; red[8 + wid] = accq; }
    __syncthreads();
    if (tid == 0) {
        float s = 0.f, q = 0.f;
#pragma unroll
        for (int w = 0; w < 8; ++w) { s += red[w]; q += red[8 + w]; }
        part_sum[c * GX + blockIdx.x] = s;
        part_sq [c * GX + blockIdx.x] = q;
    }
}

// ---------------------------------------------------------------------------
// Referee: exact fp64 re-score of flagged pairs, channel-bucketed.
// grid (64, 4): block (c, s) stages channel c's centroids (f32, bank-swizzled)
// in 64 KiB LDS once; each WAVE takes one entry (lane = 4 k's), fp64 dot.
// ---------------------------------------------------------------------------
__global__ __launch_bounds__(256) void dpq_referee(
    const float* __restrict__ x,
    const float* __restrict__ cent,
    const float* __restrict__ gamma,
    const int* __restrict__ wcount,
    const int* __restrict__ worklist,
    float* __restrict__ out)
{
    __shared__ float cl[K_ * D_];       // 64 KiB exact centroids
    const int c = blockIdx.x;
    int n = wcount[c];
    if (n > WCAP_C) n = WCAP_C;
    if (n <= 0) return;
    const int t = threadIdx.x;          // 0..255 = k row to stage
    const float sgnf = (gamma[c] < 0.0f) ? -1.0f : 1.0f;

    // stage row t with d-swizzle (d ^ (k&31)) -> conflict-free lane reads
    {
        const float* g = cent + ((size_t)c * K_ + t) * D_;
#pragma unroll 8
        for (int d = 0; d < D_; ++d)
            cl[t * D_ + (d ^ (t & 31))] = g[d];
    }
    __syncthreads();

    const int wid = t >> 6, lane = t & 63;
    for (int i = blockIdx.y * 4 + wid; i < n; i += gridDim.y * 4) {
        const int b = worklist[c * WCAP_C + i];
        const float* xr = x + ((size_t)b * C_ + c) * D_;
        double bv = -1.0e300;
        int bk = 0;
#pragma unroll
        for (int q = 0; q < 4; ++q) {
            const int k = q * 64 + lane;            // ascending per lane
            const int sw = k & 31;
            double s = 0.0;
#pragma unroll 8
            for (int d = 0; d < D_; ++d)
                s += (double)xr[d] * (double)cl[k * D_ + (d ^ sw)];
            s *= (double)sgnf;
            if (s > bv) { bv = s; bk = k; }
        }
#pragma unroll
        for (int m = 1; m <= 32; m <<= 1) {
            const double ov = __shfl_xor(bv, m);
            const int   ok = __shfl_xor(bk, m);
            if (ov > bv || (ov == bv && ok < bk)) { bv = ov; bk = ok; }
        }
        if (lane == 0) {
            const size_t idx = (size_t)b * C_ + c;
            out[idx] = (float)bk;
            out[(size_t)BC_ + idx] = (float)bv;
        }
    }
}

// ---------------------------------------------------------------------------
// Apply (fused stats + affine + centroid passthrough).
// Each block redundantly reduces the tiny (C,GX) partials -> scale/shift in
// LDS, then applies the affine; grid also covers the centroid float4 copy.
// ---------------------------------------------------------------------------
__global__ __launch_bounds__(256) void dpq_apply(
    float* __restrict__ out,
    const float* __restrict__ part_sum,
    const float* __restrict__ part_sq,
    const float* __restrict__ gamma,
    const float* __restrict__ beta,
    const float* __restrict__ cent)
{
    __shared__ float sc_s[C_], sh_s[C_];
    const int tid = threadIdx.x;
    if (tid < C_) {
        double s = 0.0, q = 0.0;
#pragma unroll
        for (int i = 0; i < GX; ++i) {
            s += (double)part_sum[tid * GX + i];
            q += (double)part_sq [tid * GX + i];
        }
        const double n    = (double)B_ * (double)K_;
        const double mean = s / n;
        const double var  = q / n - mean * mean;      // biased, matches ref
        const double sc   = fabs((double)gamma[tid]) / sqrt(var + BN_EPS);
        sc_s[tid] = (float)sc;
        sh_s[tid] = (float)((double)beta[tid] - mean * sc);
    }
    __syncthreads();

    const int idx = blockIdx.x * 256 + tid;           // over B*C, c fastest
    const int c = idx & (C_ - 1);
    const float sc = sc_s[c];
    const float sh = sh_s[c];
    if (sc == 0.0f) {                                 // gamma==0 degenerate
        out[idx] = 0.0f;
        out[(size_t)BC_ + idx] = sh;
    } else {
        out[(size_t)BC_ + idx] = fmaf(out[(size_t)BC_ + idx], sc, sh);
    }

    // centroid passthrough: 1M floats = 256K float4, first 256K threads
    if (idx < (C_ * K_ * D_) / 4) {
        ((float4*)(out + 2 * (size_t)BC_))[idx] = ((const float4*)cent)[idx];
    }
}

// ---------------------------------------------------------------------------
extern "C" void kernel_launch(void* const* d_in, const int* in_sizes, int n_in,
                              void* d_out, int out_size, void* d_ws, size_t ws_size,
                              hipStream_t stream)
{
    const float* x     = (const float*)d_in[0];
    const float* cent  = (const float*)d_in[1];
    const float* gamma = (const float*)d_in[2];
    const float* beta  = (const float*)d_in[3];
    float* out = (float*)d_out;
    float* ws  = (float*)d_ws;

    // ws layout (4B units): [0,4096) csum | [4096,4608) part_sum
    // [4608,5120) part_sq | [5120,5184) wcount[64] | [5184, +64*WCAP_C) worklist
    float* csum     = ws;
    float* part_sum = ws + 4096;
    float* part_sq  = ws + 4608;
    int*   wcount   = (int*)(ws + 5120);
    int*   worklist = (int*)(ws + 5184);

    hipLaunchKernelGGL(dpq_prep, dim3(C_), dim3(64), 0, stream,
                       cent, csum, wcount);
    dim3 g1(GX, C_);   // (8, 64)
    hipLaunchKernelGGL(dpq_mfma, g1, dim3(512), 0, stream,
                       x, cent, gamma, csum, out, part_sum, part_sq,
                       wcount, worklist);
    hipLaunchKernelGGL(dpq_referee, dim3(C_, 4), dim3(256), 0, stream,
                       x, cent, gamma, wcount, worklist, out);
    hipLaunchKernelGGL(dpq_apply, dim3(BC_ / 256), dim3(256), 0, stream,
                       out, part_sum, part_sq, gamma, beta, cent);
}